// Round 1
// baseline (367.054 us; speedup 1.0000x reference)
//
#include <hip/hip_runtime.h>

// EEGGraphClf graph-loss, fused single pass over A.
// Shapes: A=[B,N,N] fp32, F=[B,N,D] fp32, out=[B] fp32. B=64,N=1024,D=16.
//
// loss[b] = 0.2 * sum_{n,j} A[n,j]*(||f_n||^2 - f_n.f_j) / N^2
//         - 0.1 * sum_n log(deg_n + 1e-12) / N
//         + 0.1 * sum_{n,j} A[n,j]^2 / N^2
//
// Partition: 16 blocks per batch, each block = 64 rows x all 1024 cols.
// Thread t owns cols {4t..4t+3}; their features live in 64 VGPRs (no LDS in
// the per-element path). A read exactly once, coalesced float4.

#define NN      1024
#define DD      16
#define ROWS    64      // rows per block
#define TPB     256
#define CH      16      // rows per deg-reduction chunk
#define SMOOTHR 0.2f
#define DEGRR   0.1f
#define SPARSR  0.1f
#define EPSV    1e-12f

__global__ __launch_bounds__(TPB, 4)
void graph_loss_kernel(const float* __restrict__ A,
                       const float* __restrict__ F,
                       float* __restrict__ out) {
    __shared__ float fn_lds[ROWS][DD];       // 4 KB: this block's row features
    __shared__ float fn2_lds[ROWS];          // 256 B: ||f_n||^2
    __shared__ float degpart[TPB][CH + 1];   // 17 KB: per-thread deg partials (pad 17: no bank conflict)
    __shared__ float wred[4][3];             // cross-wave final reduce

    const int tid = threadIdx.x;
    const int bid = blockIdx.x;
    const int b   = bid >> 4;                // batch
    const int n0  = (bid & 15) * ROWS;       // first row of this slab

    const float* __restrict__ Fb = F + (size_t)b * NN * DD;
    const float* __restrict__ Ab = A + ((size_t)b * NN + n0) * NN;

    // ---- stage this slab's row features into LDS (coalesced float4) ----
    {
        const int r = tid >> 2, q = tid & 3;                  // 256 thr = 64 rows x 4 quads
        const float4 v = *(const float4*)(Fb + (size_t)(n0 + r) * DD + q * 4);
        *(float4*)&fn_lds[r][q * 4] = v;
    }

    // ---- column features into registers: fj[jj][d] = F[4t+jj][d] ----
    float fj[4][DD];
    #pragma unroll
    for (int jj = 0; jj < 4; ++jj) {
        const float* p = Fb + (size_t)(4 * tid + jj) * DD;
        #pragma unroll
        for (int q = 0; q < 4; ++q) {
            const float4 v = *(const float4*)(p + 4 * q);
            fj[jj][4 * q + 0] = v.x;
            fj[jj][4 * q + 1] = v.y;
            fj[jj][4 * q + 2] = v.z;
            fj[jj][4 * q + 3] = v.w;
        }
    }
    __syncthreads();

    // ---- row norms ----
    if (tid < ROWS) {
        float s = 0.f;
        #pragma unroll
        for (int d = 0; d < DD; ++d) s += fn_lds[tid][d] * fn_lds[tid][d];
        fn2_lds[tid] = s;
    }
    __syncthreads();

    float sm = 0.f;   // sum A*(||f_n||^2 - f_n.f_j)
    float sq = 0.f;   // sum A^2
    float lg = 0.f;   // sum log(deg)

    const float* __restrict__ arow = Ab + 4 * tid;
    float4 cur = *(const float4*)(arow);     // prefetch row 0

    for (int c = 0; c < ROWS / CH; ++c) {
        for (int rr = 0; rr < CH; ++rr) {
            const int r = c * CH + rr;
            const float4 a = cur;
            if (r + 1 < ROWS)                // uniform branch
                cur = *(const float4*)(arow + (size_t)(r + 1) * NN);

            const float av[4] = {a.x, a.y, a.z, a.w};

            // deg partial + sparsity
            degpart[tid][rr] = av[0] + av[1] + av[2] + av[3];
            sq += av[0] * av[0] + av[1] * av[1] + av[2] * av[2] + av[3] * av[3];

            // broadcast f_n (same-address LDS b128 reads) and its norm
            float fn[DD];
            #pragma unroll
            for (int q = 0; q < 4; ++q)
                *(float4*)&fn[4 * q] = *(const float4*)&fn_lds[r][4 * q];
            const float fn2 = fn2_lds[r];

            #pragma unroll
            for (int jj = 0; jj < 4; ++jj) {
                float dt = 0.f;
                #pragma unroll
                for (int d = 0; d < DD; ++d) dt += fj[jj][d] * fn[d];
                sm += av[jj] * (fn2 - dt);
            }
        }

        // ---- reduce deg partials for these 16 rows ----
        __syncthreads();
        {
            const int r = tid >> 4, seg = tid & 15;   // 16 rows x 16 segments
            float s = 0.f;
            #pragma unroll
            for (int i = 0; i < 16; ++i) s += degpart[seg * 16 + i][r];
            s += __shfl_xor(s, 1);
            s += __shfl_xor(s, 2);
            s += __shfl_xor(s, 4);
            s += __shfl_xor(s, 8);
            if (seg == 0) lg += logf(s + EPSV);
        }
        __syncthreads();
    }

    // ---- block reduction of the three accumulators ----
    #pragma unroll
    for (int m = 1; m < 64; m <<= 1) {
        sm += __shfl_xor(sm, m);
        sq += __shfl_xor(sq, m);
        lg += __shfl_xor(lg, m);
    }
    const int w = tid >> 6, lane = tid & 63;
    if (lane == 0) { wred[w][0] = sm; wred[w][1] = sq; wred[w][2] = lg; }
    __syncthreads();
    if (tid == 0) {
        float S = 0.f, Q = 0.f, L = 0.f;
        #pragma unroll
        for (int i = 0; i < 4; ++i) { S += wred[i][0]; Q += wred[i][1]; L += wred[i][2]; }
        const float denom = (float)NN * (float)NN;
        const float contrib = SMOOTHR * S / denom
                            - DEGRR * L / (float)NN
                            + SPARSR * Q / denom;
        atomicAdd(out + b, contrib);
    }
}

extern "C" void kernel_launch(void* const* d_in, const int* in_sizes, int n_in,
                              void* d_out, int out_size, void* d_ws, size_t ws_size,
                              hipStream_t stream) {
    const float* A = (const float*)d_in[0];   // out_adj [B,N,N]
    const float* F = (const float*)d_in[1];   // features [B,N,D]
    float* out = (float*)d_out;               // [B]

    const int B = out_size;                   // 64
    hipMemsetAsync(d_out, 0, (size_t)B * sizeof(float), stream);
    graph_loss_kernel<<<dim3(B * (NN / ROWS)), dim3(TPB), 0, stream>>>(A, F, out);
}